// Round 2
// baseline (23092.569 us; speedup 1.0000x reference)
//
#include <hip/hip_runtime.h>
#include <hip/hip_bf16.h>
#include <cstdint>
#include <cstddef>

#define HH 128
#define WW 128
#define HW 16384
#define FCH 128       // OUT_CH
#define NEGS 0.2f

__device__ __forceinline__ float leakyf(float v) { return v >= 0.f ? v : NEGS * v; }
__device__ __forceinline__ float sigmf_(float v) { return 1.f / (1.f + __expf(-v)); }

// ---------------------------------------------------------------------------
// NCHW -> NHWC transpose (for coalesced bilinear channel gathers)
// in: chunk base [NBC][128][H][W]  out: [NBC][H][W][128]
__global__ __launch_bounds__(256) void k_nhwc(const float* __restrict__ in,
                                              float* __restrict__ out) {
  __shared__ float t[32][33];
  int bx = blockIdx.x;          // x-tile (0..3)
  int cx = blockIdx.y;          // c-tile (0..3)
  int bz = blockIdx.z;          // b*H + y
  int b = bz >> 7, y = bz & 127;
  int tx = threadIdx.x & 31, tg = threadIdx.x >> 5;
#pragma unroll
  for (int i = 0; i < 4; ++i) {
    int c = cx * 32 + tg * 4 + i;
    t[tg * 4 + i][tx] = in[(((size_t)b * 128 + c) * 128 + y) * 128 + bx * 32 + tx];
  }
  __syncthreads();
#pragma unroll
  for (int i = 0; i < 4; ++i) {
    int x = bx * 32 + tg * 4 + i;
    out[(((size_t)b * 128 + y) * 128 + x) * 128 + cx * 32 + tx] = t[tx][tg * 4 + i];
  }
}

// ---------------------------------------------------------------------------
// 5x5 conv accumulate helper. IN_CB: input layout [C][npixc], else NCHW chunk.
template <int CIN, int COUT, bool IN_CB>
__device__ __forceinline__ void conv5_accum(const float* __restrict__ in,
                                            const float* __restrict__ w,
                                            float* acc, float* tile,
                                            int b, int x0, int y0, int tx, int ty,
                                            int npixc) {
  for (int c = 0; c < CIN; ++c) {
    __syncthreads();
    for (int i = threadIdx.x; i < 400; i += 256) {
      int sy = i / 20, sx = i % 20;
      int gy = y0 + sy - 2, gx = x0 + sx - 2;
      float v = 0.f;
      if (gy >= 0 && gy < HH && gx >= 0 && gx < WW) {
        size_t idx = IN_CB ? ((size_t)c * npixc + (size_t)b * HW + gy * WW + gx)
                           : (((size_t)b * CIN + c) * HW + gy * WW + gx);
        v = in[idx];
      }
      tile[i] = v;
    }
    __syncthreads();
    float v[25];
#pragma unroll
    for (int k = 0; k < 25; ++k)
      v[k] = tile[(ty + k / 5) * 20 + tx + (k % 5)];
#pragma unroll
    for (int o = 0; o < COUT; ++o) {
#pragma unroll
      for (int k = 0; k < 25; ++k)
        acc[o] = fmaf(v[k], w[(size_t)(o * CIN + c) * 25 + k], acc[o]);
    }
  }
}

// out layout: [COUT][npixc]
template <int CIN1, int CIN2, int COUT, bool LEAKY, bool IN_CB>
__global__ __launch_bounds__(256) void k_conv5(
    const float* __restrict__ in1, const float* __restrict__ in2,
    const float* __restrict__ w1, const float* __restrict__ w2,
    const float* __restrict__ b1, const float* __restrict__ b2,
    float* __restrict__ out, int npixc) {
  __shared__ float tile[400];
  int tx = threadIdx.x & 15, ty = threadIdx.x >> 4;
  int x0 = blockIdx.x * 16, y0 = blockIdx.y * 16, b = blockIdx.z;
  float acc[COUT];
#pragma unroll
  for (int o = 0; o < COUT; ++o) {
    acc[o] = b1[o];
    if constexpr (CIN2 > 0) acc[o] += b2[o];
  }
  conv5_accum<CIN1, COUT, IN_CB>(in1, w1, acc, tile, b, x0, y0, tx, ty, npixc);
  if constexpr (CIN2 > 0)
    conv5_accum<CIN2, COUT, false>(in2, w2, acc, tile, b, x0, y0, tx, ty, npixc);
  size_t pix = (size_t)b * HW + (y0 + ty) * WW + (x0 + tx);
#pragma unroll
  for (int o = 0; o < COUT; ++o) {
    float r = acc[o];
    if (LEAKY) r = leakyf(r);
    out[(size_t)o * npixc + pix] = r;
  }
}

// ---------------------------------------------------------------------------
// 3x3 conv, 384 out channels, 64 per block. in: NCHW chunk. out: [384][npixc]
template <int CIN>
__global__ __launch_bounds__(256) void k_conv3(
    const float* __restrict__ in, const float* __restrict__ w,
    const float* __restrict__ bias, float* __restrict__ out,
    int npixc, int lognbc) {
  __shared__ float tile[324];
  int tx = threadIdx.x & 15, ty = threadIdx.x >> 4;
  int x0 = blockIdx.x * 16, y0 = blockIdx.y * 16;
  int b = blockIdx.z & ((1 << lognbc) - 1), ob = blockIdx.z >> lognbc;
  int oc0 = ob * 64;
  float acc[64];
#pragma unroll
  for (int o = 0; o < 64; ++o) acc[o] = bias[oc0 + o];
  for (int c = 0; c < CIN; ++c) {
    __syncthreads();
    for (int i = threadIdx.x; i < 324; i += 256) {
      int sy = i / 18, sx = i % 18;
      int gy = y0 + sy - 1, gx = x0 + sx - 1;
      float v = 0.f;
      if (gy >= 0 && gy < HH && gx >= 0 && gx < WW)
        v = in[((size_t)b * CIN + c) * HW + gy * WW + gx];
      tile[i] = v;
    }
    __syncthreads();
    float v[9];
#pragma unroll
    for (int k = 0; k < 9; ++k)
      v[k] = tile[(ty + k / 3) * 18 + tx + (k % 3)];
#pragma unroll
    for (int o = 0; o < 64; ++o) {
#pragma unroll
      for (int k = 0; k < 9; ++k)
        acc[o] = fmaf(v[k], w[(size_t)((oc0 + o) * CIN + c) * 9 + k], acc[o]);
    }
  }
  size_t pix = (size_t)b * HW + (y0 + ty) * WW + (x0 + tx);
#pragma unroll
  for (int o = 0; o < 64; ++o)
    out[(size_t)(oc0 + o) * npixc + pix] = acc[o];
}

// ---------------------------------------------------------------------------
// Bilinear warp of h (NHWC chunk) with flow l. out: [npixc][128]
__global__ __launch_bounds__(256) void k_warp(
    const float* __restrict__ h_t, const float* __restrict__ flows,
    int l, float* __restrict__ wout, int npixc) {
  int t = threadIdx.x;
  int c = t & 127;
  size_t n = (size_t)blockIdx.x * 2 + (t >> 7);
  int b = (int)(n >> 14);
  int p = (int)(n & 16383);
  int y = p >> 7, x = p & 127;
  float fx = flows[(size_t)(2 * l) * npixc + n];
  float fy = flows[(size_t)(2 * l + 1) * npixc + n];
  float px = (float)x - fx;
  float py = (float)y - fy;
  float x0f = floorf(px), y0f = floorf(py);
  float wx = px - x0f, wy = py - y0f;
  int x0 = (int)x0f, y0i = (int)y0f;
  const float* base = h_t + (size_t)b * HW * FCH;
  float v00 = 0.f, v10 = 0.f, v01 = 0.f, v11 = 0.f;
  if ((unsigned)x0 <= 127u && (unsigned)y0i <= 127u)
    v00 = base[((size_t)y0i * WW + x0) * FCH + c];
  if ((unsigned)(x0 + 1) <= 127u && (unsigned)y0i <= 127u)
    v10 = base[((size_t)y0i * WW + (x0 + 1)) * FCH + c];
  if ((unsigned)x0 <= 127u && (unsigned)(y0i + 1) <= 127u)
    v01 = base[((size_t)(y0i + 1) * WW + x0) * FCH + c];
  if ((unsigned)(x0 + 1) <= 127u && (unsigned)(y0i + 1) <= 127u)
    v11 = base[((size_t)(y0i + 1) * WW + (x0 + 1)) * FCH + c];
  float v = (1.f - wy) * ((1.f - wx) * v00 + wx * v10) +
            wy * ((1.f - wx) * v01 + wx * v11);
  wout[n * FCH + c] = v;
}

// ---------------------------------------------------------------------------
// h2h GEMM for one l: C[384][npixc] += ret_w[:, l*128:(l+1)*128] x warp^T
// rows 0..255 accumulate into i2hbuf; rows 256..383 into h2h2 (init on FIRST).
template <bool FIRST>
__global__ __launch_bounds__(256) void k_gemm_ret(
    const float* __restrict__ w, const float* __restrict__ bias,
    const float* __restrict__ Bm, float* __restrict__ i2hbuf,
    float* __restrict__ h2h2, int l, int npixc) {
  __shared__ float As[64][17];
  __shared__ float Bs[64][17];
  int t = threadIdx.x;
  int n0 = blockIdx.x * 64, m0 = blockIdx.y * 64;
  int tm = (t >> 4) * 4, tn = (t & 15) * 4;
  float acc[4][4] = {};
  int r = t >> 2, kk = (t & 3) * 4;
  for (int k0 = 0; k0 < 128; k0 += 16) {
    __syncthreads();
    float4 va = *(const float4*)&w[(size_t)(m0 + r) * 640 + l * 128 + k0 + kk];
    As[r][kk] = va.x; As[r][kk + 1] = va.y; As[r][kk + 2] = va.z; As[r][kk + 3] = va.w;
    float4 vb = *(const float4*)&Bm[((size_t)(n0 + r)) * 128 + k0 + kk];
    Bs[r][kk] = vb.x; Bs[r][kk + 1] = vb.y; Bs[r][kk + 2] = vb.z; Bs[r][kk + 3] = vb.w;
    __syncthreads();
#pragma unroll
    for (int k = 0; k < 16; ++k) {
      float a[4], bb[4];
#pragma unroll
      for (int i = 0; i < 4; ++i) { a[i] = As[tm + i][k]; bb[i] = Bs[tn + i][k]; }
#pragma unroll
      for (int i = 0; i < 4; ++i)
#pragma unroll
        for (int j = 0; j < 4; ++j)
          acc[i][j] = fmaf(a[i], bb[j], acc[i][j]);
    }
  }
#pragma unroll
  for (int i = 0; i < 4; ++i) {
    int m = m0 + tm + i;
#pragma unroll
    for (int j = 0; j < 4; ++j) {
      int n = n0 + tn + j;
      float v = acc[i][j];
      if (FIRST) v += bias[m];
      if (m < 256) {
        i2hbuf[(size_t)m * npixc + n] += v;
      } else {
        float* p = &h2h2[(size_t)(m - 256) * npixc + n];
        if (FIRST) *p = v; else *p += v;
      }
    }
  }
}

// ---------------------------------------------------------------------------
// Gates: h_new = u*h + (1-u)*leaky(i2h2 + r*h2h2), r/u from pre-summed chunks.
__global__ __launch_bounds__(256) void k_gates(
    const float* __restrict__ i2hbuf, const float* __restrict__ h2h2,
    const float* __restrict__ hprev, float* __restrict__ hout, int npixc) {
  size_t n = (size_t)blockIdx.x * 256 + threadIdx.x;
  int b = (int)(n >> 14), p = (int)(n & 16383);
  for (int cc = 0; cc < 128; ++cc) {
    float rv = i2hbuf[(size_t)cc * npixc + n];
    float uv = i2hbuf[(size_t)(cc + 128) * npixc + n];
    float mv = i2hbuf[(size_t)(cc + 256) * npixc + n];
    float hv = h2h2[(size_t)cc * npixc + n];
    float hp = hprev[((size_t)b * 128 + cc) * HW + p];
    float r = sigmf_(rv), u = sigmf_(uv);
    float nm = leakyf(fmaf(r, hv, mv));
    hout[((size_t)b * 128 + cc) * HW + p] = u * hp + (1.f - u) * nm;
  }
}

// ---------------------------------------------------------------------------
extern "C" void kernel_launch(void* const* d_in, const int* in_sizes, int n_in,
                              void* d_out, int out_size, void* d_ws, size_t ws_size,
                              hipStream_t stream) {
  const float* x       = (const float*)d_in[0];
  const float* hp1     = (const float*)d_in[1];
  const float* hp2     = (const float*)d_in[2];
  const float* i2h_w1  = (const float*)d_in[3];
  const float* i2h_b1  = (const float*)d_in[4];
  const float* i2f_w1  = (const float*)d_in[5];
  const float* i2f_b1  = (const float*)d_in[6];
  const float* h2f_w1  = (const float*)d_in[7];
  const float* h2f_b1  = (const float*)d_in[8];
  const float* flow_w1 = (const float*)d_in[9];
  const float* flow_b1 = (const float*)d_in[10];
  const float* ret_w1  = (const float*)d_in[11];
  const float* ret_b1  = (const float*)d_in[12];
  const float* i2h_w2  = (const float*)d_in[13];
  const float* i2h_b2  = (const float*)d_in[14];
  const float* i2f_w2  = (const float*)d_in[15];
  const float* i2f_b2  = (const float*)d_in[16];
  const float* h2f_w2  = (const float*)d_in[17];
  const float* h2f_b2  = (const float*)d_in[18];
  const float* flow_w2 = (const float*)d_in[19];
  const float* flow_b2 = (const float*)d_in[20];
  const float* ret_w2  = (const float*)d_in[21];
  const float* ret_b2  = (const float*)d_in[22];
  float* out = (float*)d_out;

  // Choose largest batch-chunk NBC in {8,4,2,1} whose workspace fits ws_size.
  // Per-chunk floats: (384 + 128 + 128 + 128 + 32 + 10) * NBC*HW = 810*NBC*HW.
  int NBC = 8, lognbc = 3;
  while (NBC > 1 && (size_t)810 * NBC * HW * sizeof(float) > ws_size) {
    NBC >>= 1; lognbc--;
  }
  const int npixc = NBC * HW;

  float* ws = (float*)d_ws;
  float* i2hbuf = ws;                                 // 384*npixc
  float* h2h2   = i2hbuf + (size_t)384 * npixc;       // 128*npixc
  float* warpb  = h2h2 + (size_t)128 * npixc;         // 128*npixc ([npixc][128])
  float* h_t    = warpb + (size_t)128 * npixc;        // 128*npixc (NHWC)
  float* f1b    = h_t + (size_t)128 * npixc;          // 32*npixc
  float* flowsb = f1b + (size_t)32 * npixc;           // 10*npixc

  dim3 blk(256);

  for (int b0 = 0; b0 < 8; b0 += NBC) {
    const float* xc   = x + (size_t)b0 * 64 * HW;
    const float* hp1c = hp1 + (size_t)b0 * 128 * HW;
    const float* hp2c = hp2 + (size_t)b0 * 128 * HW;
    float* h1c = out + (size_t)b0 * 128 * HW;   // h1 lives in d_out temporarily

    // ---------------- step 1 ----------------
    k_nhwc<<<dim3(4, 4, NBC * 128), blk, 0, stream>>>(hp1c, h_t);
    k_conv5<64, 128, 32, true, false><<<dim3(8, 8, NBC), blk, 0, stream>>>(
        xc, hp1c, i2f_w1, h2f_w1, i2f_b1, h2f_b1, f1b, npixc);
    k_conv5<32, 0, 10, false, true><<<dim3(8, 8, NBC), blk, 0, stream>>>(
        f1b, nullptr, flow_w1, nullptr, flow_b1, nullptr, flowsb, npixc);
    k_conv3<64><<<dim3(8, 8, NBC * 6), blk, 0, stream>>>(xc, i2h_w1, i2h_b1,
                                                         i2hbuf, npixc, lognbc);
    for (int l = 0; l < 5; ++l) {
      k_warp<<<dim3(npixc / 2), blk, 0, stream>>>(h_t, flowsb, l, warpb, npixc);
      if (l == 0)
        k_gemm_ret<true><<<dim3(npixc / 64, 6), blk, 0, stream>>>(
            ret_w1, ret_b1, warpb, i2hbuf, h2h2, l, npixc);
      else
        k_gemm_ret<false><<<dim3(npixc / 64, 6), blk, 0, stream>>>(
            ret_w1, ret_b1, warpb, i2hbuf, h2h2, l, npixc);
    }
    k_gates<<<dim3(npixc / 256), blk, 0, stream>>>(i2hbuf, h2h2, hp1c, h1c, npixc);

    // ---------------- step 2 ----------------
    k_nhwc<<<dim3(4, 4, NBC * 128), blk, 0, stream>>>(hp2c, h_t);
    k_conv5<128, 128, 32, true, false><<<dim3(8, 8, NBC), blk, 0, stream>>>(
        h1c, hp2c, i2f_w2, h2f_w2, i2f_b2, h2f_b2, f1b, npixc);
    k_conv5<32, 0, 10, false, true><<<dim3(8, 8, NBC), blk, 0, stream>>>(
        f1b, nullptr, flow_w2, nullptr, flow_b2, nullptr, flowsb, npixc);
    k_conv3<128><<<dim3(8, 8, NBC * 6), blk, 0, stream>>>(h1c, i2h_w2, i2h_b2,
                                                          i2hbuf, npixc, lognbc);
    for (int l = 0; l < 5; ++l) {
      k_warp<<<dim3(npixc / 2), blk, 0, stream>>>(h_t, flowsb, l, warpb, npixc);
      if (l == 0)
        k_gemm_ret<true><<<dim3(npixc / 64, 6), blk, 0, stream>>>(
            ret_w2, ret_b2, warpb, i2hbuf, h2h2, l, npixc);
      else
        k_gemm_ret<false><<<dim3(npixc / 64, 6), blk, 0, stream>>>(
            ret_w2, ret_b2, warpb, i2hbuf, h2h2, l, npixc);
    }
    k_gates<<<dim3(npixc / 256), blk, 0, stream>>>(i2hbuf, h2h2, hp2c,
                                                   out + (size_t)b0 * 128 * HW, npixc);
  }
}

// Round 3
// 4334.565 us; speedup vs baseline: 5.3275x; 5.3275x over previous
//
#include <hip/hip_runtime.h>
#include <hip/hip_bf16.h>
#include <cstdint>
#include <cstddef>

#define HH 128
#define WW 128
#define HW 16384
#define NEGS 0.2f

typedef __attribute__((ext_vector_type(8))) short short8;
typedef __attribute__((ext_vector_type(4))) float f32x4;

__device__ __forceinline__ float leakyf(float v) { return v >= 0.f ? v : NEGS * v; }
__device__ __forceinline__ float sigmf_(float v) { return 1.f / (1.f + __expf(-v)); }

// ---------------------------------------------------------------------------
// Pack conv weights fp32 [OC][CINs][T] -> bf16 dst[oc*KK + kbase + t*CINs + c]
__global__ __launch_bounds__(256) void k_pack(const float* __restrict__ src,
                                              __hip_bfloat16* __restrict__ dst,
                                              int OC, int CINs, int T, int kbase,
                                              int KK) {
  int i = blockIdx.x * 256 + threadIdx.x;
  if (i >= OC * CINs * T) return;
  int t = i % T;
  int c = (i / T) % CINs;
  int oc = i / (T * CINs);
  dst[(size_t)oc * KK + kbase + t * CINs + c] = __float2bfloat16(src[i]);
}

// ---------------------------------------------------------------------------
// NCHW fp32 -> NHWC bf16 (chunk-local). grid (W/32, CH/32, NBC*128)
template <int CH>
__global__ __launch_bounds__(256) void k_cast_nhwc(const float* __restrict__ in,
                                                   __hip_bfloat16* __restrict__ out) {
  __shared__ float t[32][33];
  int bx = blockIdx.x;
  int cx = blockIdx.y;
  int bz = blockIdx.z;
  int b = bz >> 7, y = bz & 127;
  int tx = threadIdx.x & 31, tg = threadIdx.x >> 5;
#pragma unroll
  for (int i = 0; i < 4; ++i) {
    int c = cx * 32 + tg * 4 + i;
    t[tg * 4 + i][tx] = in[(((size_t)b * CH + c) * 128 + y) * 128 + bx * 32 + tx];
  }
  __syncthreads();
#pragma unroll
  for (int i = 0; i < 4; ++i) {
    int x = bx * 32 + tg * 4 + i;
    size_t pix = ((size_t)b * 128 + y) * 128 + x;
    out[pix * CH + cx * 32 + tx] = __float2bfloat16(t[tx][tg * 4 + i]);
  }
}

// ---------------------------------------------------------------------------
// One conv segment (tap) K-chunk accumulate.
template <int CS, int NFR, int KK>
__device__ __forceinline__ void mc_seg(const short* __restrict__ src,
                                       const short* __restrict__ wrow,
                                       int kbase, int dy, int dx,
                                       const int* py_r, const int* px_m,
                                       int lk, f32x4 (&acc)[4][NFR]) {
  const short* aptr[4];
  bool av[4];
#pragma unroll
  for (int fm = 0; fm < 4; ++fm) {
    int yy = (py_r[fm] & 127) + dy;
    int bb = py_r[fm] >> 7;
    int xx = px_m[fm] + dx;
    bool ok = ((unsigned)yy < 128u) && ((unsigned)xx < 128u);
    av[fm] = ok;
    int ycl = ok ? yy : 0;
    int xcl = ok ? xx : 0;
    size_t pix = ((size_t)(bb << 7) + ycl) * 128 + xcl;
    aptr[fm] = src + pix * CS + lk;
  }
  const short8 z = {0, 0, 0, 0, 0, 0, 0, 0};
#pragma unroll
  for (int c0 = 0; c0 < CS; c0 += 32) {
    short8 bf[NFR];
#pragma unroll
    for (int fn = 0; fn < NFR; ++fn)
      bf[fn] = *(const short8*)&wrow[(size_t)fn * 16 * KK + kbase + c0];
    short8 af[4];
#pragma unroll
    for (int fm = 0; fm < 4; ++fm) {
      short8 v = *(const short8*)(aptr[fm] + c0);
      af[fm] = av[fm] ? v : z;
    }
#pragma unroll
    for (int fm = 0; fm < 4; ++fm)
#pragma unroll
      for (int fn = 0; fn < NFR; ++fn)
        acc[fm][fn] = __builtin_amdgcn_mfma_f32_16x16x32_bf16(
            af[fm], bf[fn], acc[fm][fn], 0, 0, 0);
  }
}

// ---------------------------------------------------------------------------
// Unified MFMA implicit-GEMM conv.
// in1/in2: NHWC bf16 (chunk-local). wb: [oc][KK] bf16, k = tap*CIN + c,
// in1 taps first then in2 taps. out: [pix][ostride] fp32 or bf16.
// BN=128: 1 row/block, grid.y = 384/128. BN=32: 1 row. BN=16: 2 rows.
template <int CIN1, int CIN2, int RAD, int BN, bool LEAKY, bool OUTBF16>
__global__ __launch_bounds__(256) void k_mconv(
    const short* __restrict__ in1, const short* __restrict__ in2,
    const short* __restrict__ wb, const float* __restrict__ bias1,
    const float* __restrict__ bias2, void* __restrict__ outp,
    int nout, int ostride) {
  constexpr int KD = 2 * RAD + 1;
  constexpr int T = KD * KD;
  constexpr int KK = T * (CIN1 + CIN2);
  constexpr int WN = (BN >= 32) ? 2 : 1;
  constexpr int ROWS = (WN == 2) ? 1 : 2;
  constexpr int NFR = BN / (16 * WN);  // 128->4, 32->1, 16->1

  int tid = threadIdx.x, lane = tid & 63, wid = tid >> 6;
  int wm = wid / WN, wn = wid % WN;
  int l15 = lane & 15, lk = (lane >> 4) * 8;
  int r0 = blockIdx.x * ROWS;
  int ocb = blockIdx.y * BN + wn * (NFR * 16);

  f32x4 acc[4][NFR];
#pragma unroll
  for (int i = 0; i < 4; ++i)
#pragma unroll
    for (int j = 0; j < NFR; ++j) {
      acc[i][j][0] = 0.f; acc[i][j][1] = 0.f;
      acc[i][j][2] = 0.f; acc[i][j][3] = 0.f;
    }

  int py_r[4], px_m[4];
#pragma unroll
  for (int fm = 0; fm < 4; ++fm) {
    int m = wm * 64 + fm * 16 + l15;
    py_r[fm] = r0 + (m >> 7);
    px_m[fm] = m & 127;
  }

  const short* wrow = wb + (size_t)(ocb + l15) * KK + lk;

#pragma unroll 1
  for (int s = 0; s < T; ++s) {
    int dy = s / KD - RAD, dx = s % KD - RAD;
    mc_seg<CIN1, NFR, KK>(in1, wrow, s * CIN1, dy, dx, py_r, px_m, lk, acc);
  }
  if constexpr (CIN2 > 0) {
#pragma unroll 1
    for (int s = 0; s < T; ++s) {
      int dy = s / KD - RAD, dx = s % KD - RAD;
      mc_seg<CIN2, NFR, KK>(in2, wrow, T * CIN1 + s * CIN2, dy, dx, py_r, px_m,
                            lk, acc);
    }
  }

  // epilogue
#pragma unroll
  for (int fn = 0; fn < NFR; ++fn) {
    int ocx = ocb + fn * 16 + l15;
    float bv = 0.f;
    if (ocx < nout) {
      bv = bias1[ocx];
      if (bias2) bv += bias2[ocx];
    }
#pragma unroll
    for (int fm = 0; fm < 4; ++fm) {
#pragma unroll
      for (int j = 0; j < 4; ++j) {
        int m = wm * 64 + fm * 16 + (lane >> 4) * 4 + j;
        int row = r0 + (m >> 7);
        size_t pix = (size_t)row * 128 + (m & 127);
        float v = acc[fm][fn][j] + bv;
        if (LEAKY) v = leakyf(v);
        if (ocx < nout) {
          if constexpr (OUTBF16)
            ((__hip_bfloat16*)outp)[pix * ostride + ocx] = __float2bfloat16(v);
          else
            ((float*)outp)[pix * ostride + ocx] = v;
        }
      }
    }
  }
}

// ---------------------------------------------------------------------------
// Bilinear warp for all 5 flows. h_t: NHWC bf16 [npixc][128].
// flows: [pix][16] fp32 (cols 0..9 = (fx,fy) x 5). out: [pix][640] bf16.
__global__ __launch_bounds__(256) void k_warp5(
    const __hip_bfloat16* __restrict__ h_t, const float* __restrict__ flows,
    __hip_bfloat16* __restrict__ wout) {
  int t = threadIdx.x;
  int c = t & 127;
  size_t n = (size_t)blockIdx.x * 2 + (t >> 7);
  int b = (int)(n >> 14);
  int p = (int)(n & 16383);
  int y = p >> 7, x = p & 127;
  const __hip_bfloat16* base = h_t + (size_t)b * HW * 128;
#pragma unroll 1
  for (int l = 0; l < 5; ++l) {
    float fx = flows[n * 16 + 2 * l];
    float fy = flows[n * 16 + 2 * l + 1];
    float px = (float)x - fx;
    float py = (float)y - fy;
    float x0f = floorf(px), y0f = floorf(py);
    float wx = px - x0f, wy = py - y0f;
    int x0 = (int)x0f, y0i = (int)y0f;
    float v00 = 0.f, v10 = 0.f, v01 = 0.f, v11 = 0.f;
    if ((unsigned)x0 <= 127u && (unsigned)y0i <= 127u)
      v00 = __bfloat162float(base[((size_t)y0i * WW + x0) * 128 + c]);
    if ((unsigned)(x0 + 1) <= 127u && (unsigned)y0i <= 127u)
      v10 = __bfloat162float(base[((size_t)y0i * WW + (x0 + 1)) * 128 + c]);
    if ((unsigned)x0 <= 127u && (unsigned)(y0i + 1) <= 127u)
      v01 = __bfloat162float(base[((size_t)(y0i + 1) * WW + x0) * 128 + c]);
    if ((unsigned)(x0 + 1) <= 127u && (unsigned)(y0i + 1) <= 127u)
      v11 = __bfloat162float(base[((size_t)(y0i + 1) * WW + (x0 + 1)) * 128 + c]);
    float v = (1.f - wy) * ((1.f - wx) * v00 + wx * v10) +
              wy * ((1.f - wx) * v01 + wx * v11);
    wout[n * 640 + l * 128 + c] = __float2bfloat16(v);
  }
}

// ---------------------------------------------------------------------------
// Gates. i2h/h2h: [pix][384] fp32 NHWC. hprev/hout: NCHW fp32 (chunk-local).
__global__ __launch_bounds__(256) void k_gates(
    const float* __restrict__ i2h, const float* __restrict__ h2h,
    const float* __restrict__ hprev, float* __restrict__ hout) {
  size_t n = (size_t)blockIdx.x * 256 + threadIdx.x;
  int b = (int)(n >> 14), p = (int)(n & 16383);
#pragma unroll 1
  for (int cc = 0; cc < 128; ++cc) {
    float rv = i2h[n * 384 + cc] + h2h[n * 384 + cc];
    float uv = i2h[n * 384 + 128 + cc] + h2h[n * 384 + 128 + cc];
    float mv = i2h[n * 384 + 256 + cc];
    float hv = h2h[n * 384 + 256 + cc];
    float hp = hprev[((size_t)b * 128 + cc) * HW + p];
    float r = sigmf_(rv), u = sigmf_(uv);
    float nm = leakyf(fmaf(r, hv, mv));
    hout[((size_t)b * 128 + cc) * HW + p] = u * hp + (1.f - u) * nm;
  }
}

// ---------------------------------------------------------------------------
extern "C" void kernel_launch(void* const* d_in, const int* in_sizes, int n_in,
                              void* d_out, int out_size, void* d_ws, size_t ws_size,
                              hipStream_t stream) {
  const float* x       = (const float*)d_in[0];
  const float* hp1     = (const float*)d_in[1];
  const float* hp2     = (const float*)d_in[2];
  const float* i2h_w1  = (const float*)d_in[3];
  const float* i2h_b1  = (const float*)d_in[4];
  const float* i2f_w1  = (const float*)d_in[5];
  const float* i2f_b1  = (const float*)d_in[6];
  const float* h2f_w1  = (const float*)d_in[7];
  const float* h2f_b1  = (const float*)d_in[8];
  const float* flow_w1 = (const float*)d_in[9];
  const float* flow_b1 = (const float*)d_in[10];
  const float* ret_w1  = (const float*)d_in[11];
  const float* ret_b1  = (const float*)d_in[12];
  const float* i2h_w2  = (const float*)d_in[13];
  const float* i2h_b2  = (const float*)d_in[14];
  const float* i2f_w2  = (const float*)d_in[15];
  const float* i2f_b2  = (const float*)d_in[16];
  const float* h2f_w2  = (const float*)d_in[17];
  const float* h2f_b2  = (const float*)d_in[18];
  const float* flow_w2 = (const float*)d_in[19];
  const float* flow_b2 = (const float*)d_in[20];
  const float* ret_w2  = (const float*)d_in[21];
  const float* ret_b2  = (const float*)d_in[22];
  float* out = (float*)d_out;

  // ---- workspace layout ----
  // weights (bf16 elems):
  const size_t nWb3_1 = (size_t)384 * 576;
  const size_t nWb3_2 = (size_t)384 * 1152;
  const size_t nWbf1  = (size_t)32 * 4800;   // 25*(64+128)
  const size_t nWbf2  = (size_t)32 * 6400;   // 25*(128+128)
  const size_t nWfl   = (size_t)16 * 800;
  const size_t nWret  = (size_t)384 * 640;
  const size_t wtot = nWb3_1 + nWb3_2 + nWbf1 + nWbf2 + 2 * nWfl + 2 * nWret;

  // activation bytes per pixel: i2h 1536 + h2h 1536 + warp5 1280 + h_t 256
  //                            + xb 256 + f1 64 + flows 64 = 4992
  int NBC = 8;
  while (NBC > 1 &&
         wtot * 2 + (size_t)4992 * NBC * HW > ws_size)
    NBC >>= 1;
  const int npixc = NBC * HW;

  __hip_bfloat16* wbase = (__hip_bfloat16*)d_ws;
  __hip_bfloat16* Wb3_1 = wbase;
  __hip_bfloat16* Wb3_2 = Wb3_1 + nWb3_1;
  __hip_bfloat16* Wbf1  = Wb3_2 + nWb3_2;
  __hip_bfloat16* Wbf2  = Wbf1 + nWbf1;
  __hip_bfloat16* Wfl1  = Wbf2 + nWbf2;
  __hip_bfloat16* Wfl2  = Wfl1 + nWfl;
  __hip_bfloat16* Wret1 = Wfl2 + nWfl;
  __hip_bfloat16* Wret2 = Wret1 + nWret;

  char* abase = (char*)(Wret2 + nWret);
  float* i2hbuf = (float*)abase;                          // [npixc][384] f32
  float* h2hbuf = i2hbuf + (size_t)npixc * 384;           // [npixc][384] f32
  __hip_bfloat16* warpb5 = (__hip_bfloat16*)(h2hbuf + (size_t)npixc * 384); // [npixc][640]
  __hip_bfloat16* h_t = warpb5 + (size_t)npixc * 640;     // [npixc][128]
  __hip_bfloat16* xb  = h_t + (size_t)npixc * 128;        // [npixc][<=128]
  __hip_bfloat16* f1b = xb + (size_t)npixc * 128;         // [npixc][32]
  float* flowsb = (float*)(f1b + (size_t)npixc * 32);     // [npixc][16] f32

  dim3 blk(256);
  auto packs = [&](const float* src, __hip_bfloat16* dst, int OC, int CINs,
                   int T, int kbase, int KK) {
    int n = OC * CINs * T;
    k_pack<<<dim3((n + 255) / 256), blk, 0, stream>>>(src, dst, OC, CINs, T,
                                                      kbase, KK);
  };
  // ---- pack all weights (once) ----
  packs(i2h_w1, Wb3_1, 384, 64, 9, 0, 576);
  packs(i2h_w2, Wb3_2, 384, 128, 9, 0, 1152);
  packs(i2f_w1, Wbf1, 32, 64, 25, 0, 4800);
  packs(h2f_w1, Wbf1, 32, 128, 25, 1600, 4800);
  packs(i2f_w2, Wbf2, 32, 128, 25, 0, 6400);
  packs(h2f_w2, Wbf2, 32, 128, 25, 3200, 6400);
  packs(flow_w1, Wfl1, 10, 32, 25, 0, 800);
  packs(flow_w2, Wfl2, 10, 32, 25, 0, 800);
  packs(ret_w1, Wret1, 384, 640, 1, 0, 640);
  packs(ret_w2, Wret2, 384, 640, 1, 0, 640);

  for (int b0 = 0; b0 < 8; b0 += NBC) {
    const float* xc   = x + (size_t)b0 * 64 * HW;
    const float* hp1c = hp1 + (size_t)b0 * 128 * HW;
    const float* hp2c = hp2 + (size_t)b0 * 128 * HW;
    float* h1c = out + (size_t)b0 * 128 * HW;

    // ================= step 1 =================
    k_cast_nhwc<128><<<dim3(4, 4, NBC * 128), blk, 0, stream>>>(hp1c, h_t);
    k_cast_nhwc<64><<<dim3(4, 2, NBC * 128), blk, 0, stream>>>(xc, xb);
    // f1 = leaky(i2f*x + h2f*h)
    k_mconv<64, 128, 2, 32, true, true><<<dim3(NBC * 128, 1), blk, 0, stream>>>(
        (const short*)xb, (const short*)h_t, (const short*)Wbf1, i2f_b1,
        h2f_b1, f1b, 32, 32);
    // flows
    k_mconv<32, 0, 2, 16, false, false><<<dim3(NBC * 64, 1), blk, 0, stream>>>(
        (const short*)f1b, nullptr, (const short*)Wfl1, flow_b1, nullptr,
        flowsb, 10, 16);
    // i2h conv3
    k_mconv<64, 0, 1, 128, false, false><<<dim3(NBC * 128, 3), blk, 0, stream>>>(
        (const short*)xb, nullptr, (const short*)Wb3_1, i2h_b1, nullptr,
        i2hbuf, 384, 384);
    // warp + ret GEMM
    k_warp5<<<dim3(npixc / 2), blk, 0, stream>>>(h_t, flowsb, warpb5);
    k_mconv<640, 0, 0, 128, false, false><<<dim3(NBC * 128, 3), blk, 0, stream>>>(
        (const short*)warpb5, nullptr, (const short*)Wret1, ret_b1, nullptr,
        h2hbuf, 384, 384);
    k_gates<<<dim3(npixc / 256), blk, 0, stream>>>(i2hbuf, h2hbuf, hp1c, h1c);

    // ================= step 2 =================
    k_cast_nhwc<128><<<dim3(4, 4, NBC * 128), blk, 0, stream>>>(hp2c, h_t);
    k_cast_nhwc<128><<<dim3(4, 4, NBC * 128), blk, 0, stream>>>(h1c, xb);
    k_mconv<128, 128, 2, 32, true, true><<<dim3(NBC * 128, 1), blk, 0, stream>>>(
        (const short*)xb, (const short*)h_t, (const short*)Wbf2, i2f_b2,
        h2f_b2, f1b, 32, 32);
    k_mconv<32, 0, 2, 16, false, false><<<dim3(NBC * 64, 1), blk, 0, stream>>>(
        (const short*)f1b, nullptr, (const short*)Wfl2, flow_b2, nullptr,
        flowsb, 10, 16);
    k_mconv<128, 0, 1, 128, false, false><<<dim3(NBC * 128, 3), blk, 0, stream>>>(
        (const short*)xb, nullptr, (const short*)Wb3_2, i2h_b2, nullptr,
        i2hbuf, 384, 384);
    k_warp5<<<dim3(npixc / 2), blk, 0, stream>>>(h_t, flowsb, warpb5);
    k_mconv<640, 0, 0, 128, false, false><<<dim3(NBC * 128, 3), blk, 0, stream>>>(
        (const short*)warpb5, nullptr, (const short*)Wret2, ret_b2, nullptr,
        h2hbuf, 384, 384);
    k_gates<<<dim3(npixc / 256), blk, 0, stream>>>(
        i2hbuf, h2hbuf, hp2c, out + (size_t)b0 * 128 * HW);
  }
}

// Round 4
// 2980.932 us; speedup vs baseline: 7.7468x; 1.4541x over previous
//
#include <hip/hip_runtime.h>
#include <hip/hip_bf16.h>
#include <cstdint>
#include <cstddef>

#define HH 128
#define WW 128
#define HW 16384
#define NEGS 0.2f

typedef __attribute__((ext_vector_type(8))) short short8;
typedef __attribute__((ext_vector_type(4))) short s16x4;
typedef __attribute__((ext_vector_type(4))) float f32x4;

__device__ __forceinline__ float leakyf(float v) { return v >= 0.f ? v : NEGS * v; }
__device__ __forceinline__ float sigmf_(float v) { return 1.f / (1.f + __expf(-v)); }
__device__ __forceinline__ float bf2f(short s) {
  union { float f; unsigned u; } x;
  x.u = ((unsigned)(unsigned short)s) << 16;
  return x.f;
}
__device__ __forceinline__ short f2bf(float v) {
  __hip_bfloat16 h = __float2bfloat16(v);
  return *(short*)&h;
}

// ---------------------------------------------------------------------------
// Pack conv weights fp32 [OC][CINs][T] -> bf16 dst[oc*KK + kbase + t*CINs + c]
__global__ __launch_bounds__(256) void k_pack(const float* __restrict__ src,
                                              __hip_bfloat16* __restrict__ dst,
                                              int OC, int CINs, int T, int kbase,
                                              int KK) {
  int i = blockIdx.x * 256 + threadIdx.x;
  if (i >= OC * CINs * T) return;
  int t = i % T;
  int c = (i / T) % CINs;
  int oc = i / (T * CINs);
  dst[(size_t)oc * KK + kbase + t * CINs + c] = __float2bfloat16(src[i]);
}

// ---------------------------------------------------------------------------
// NCHW fp32 -> NHWC bf16 (chunk-local). grid (W/32, CH/32, NBC*128)
template <int CH>
__global__ __launch_bounds__(256) void k_cast_nhwc(const float* __restrict__ in,
                                                   __hip_bfloat16* __restrict__ out) {
  __shared__ float t[32][33];
  int bx = blockIdx.x;
  int cx = blockIdx.y;
  int bz = blockIdx.z;
  int b = bz >> 7, y = bz & 127;
  int tx = threadIdx.x & 31, tg = threadIdx.x >> 5;
#pragma unroll
  for (int i = 0; i < 4; ++i) {
    int c = cx * 32 + tg * 4 + i;
    t[tg * 4 + i][tx] = in[(((size_t)b * CH + c) * 128 + y) * 128 + bx * 32 + tx];
  }
  __syncthreads();
#pragma unroll
  for (int i = 0; i < 4; ++i) {
    int x = bx * 32 + tg * 4 + i;
    size_t pix = ((size_t)b * 128 + y) * 128 + x;
    out[pix * CH + cx * 32 + tx] = __float2bfloat16(t[tx][tg * 4 + i]);
  }
}

// ---------------------------------------------------------------------------
// NHWC fp32 [npixc][128] -> NCHW fp32. grid (4, 4, NBC*128)
__global__ __launch_bounds__(256) void k_tonchw(const float* __restrict__ in,
                                                float* __restrict__ out) {
  __shared__ float t[32][33];
  int bx = blockIdx.x;
  int cx = blockIdx.y;
  int bz = blockIdx.z;
  int b = bz >> 7, y = bz & 127;
  int tx = threadIdx.x & 31, tg = threadIdx.x >> 5;
#pragma unroll
  for (int i = 0; i < 4; ++i) {
    int x = bx * 32 + tg * 4 + i;
    t[tg * 4 + i][tx] = in[(((size_t)b * 128 + y) * 128 + x) * 128 + cx * 32 + tx];
  }
  __syncthreads();
#pragma unroll
  for (int i = 0; i < 4; ++i) {
    int c = cx * 32 + tg * 4 + i;
    out[(((size_t)b * 128 + c) * 128 + y) * 128 + bx * 32 + tx] = t[tx][tg * 4 + i];
  }
}

// ---------------------------------------------------------------------------
// One conv segment (tap) K-chunk accumulate.
template <int CS, int NFR, int KK>
__device__ __forceinline__ void mc_seg(const short* __restrict__ src,
                                       const short* __restrict__ wrow,
                                       int kbase, int dy, int dx,
                                       const int* py_r, const int* px_m,
                                       int lk, f32x4 (&acc)[4][NFR]) {
  const short* aptr[4];
  bool av[4];
#pragma unroll
  for (int fm = 0; fm < 4; ++fm) {
    int yy = (py_r[fm] & 127) + dy;
    int bb = py_r[fm] >> 7;
    int xx = px_m[fm] + dx;
    bool ok = ((unsigned)yy < 128u) && ((unsigned)xx < 128u);
    av[fm] = ok;
    int ycl = ok ? yy : 0;
    int xcl = ok ? xx : 0;
    size_t pix = ((size_t)(bb << 7) + ycl) * 128 + xcl;
    aptr[fm] = src + pix * CS + lk;
  }
  const short8 z = {0, 0, 0, 0, 0, 0, 0, 0};
#pragma unroll
  for (int c0 = 0; c0 < CS; c0 += 32) {
    short8 bf[NFR];
#pragma unroll
    for (int fn = 0; fn < NFR; ++fn)
      bf[fn] = *(const short8*)&wrow[(size_t)fn * 16 * KK + kbase + c0];
    short8 af[4];
#pragma unroll
    for (int fm = 0; fm < 4; ++fm) {
      short8 v = *(const short8*)(aptr[fm] + c0);
      af[fm] = av[fm] ? v : z;
    }
#pragma unroll
    for (int fm = 0; fm < 4; ++fm)
#pragma unroll
      for (int fn = 0; fn < NFR; ++fn)
        acc[fm][fn] = __builtin_amdgcn_mfma_f32_16x16x32_bf16(
            af[fm], bf[fn], acc[fm][fn], 0, 0, 0);
  }
}

// ---------------------------------------------------------------------------
// Unified MFMA implicit-GEMM conv.
// in1/in2: NHWC bf16 (chunk-local). wb: [oc][KK] bf16, k = tap*CIN + c,
// in1 taps first then in2 taps.
// MODE 0: store fp32 [pix][ostride]; MODE 1: store bf16 [pix][ostride];
// MODE 2 (ret): oc<256 accumulate into outp fp32 [pix][384];
//               oc>=256 store to outp2 fp32 [pix][128].
template <int CIN1, int CIN2, int RAD, int BN, bool LEAKY, int MODE>
__global__ __launch_bounds__(256) void k_mconv(
    const short* __restrict__ in1, const short* __restrict__ in2,
    const short* __restrict__ wb, const float* __restrict__ bias1,
    const float* __restrict__ bias2, void* __restrict__ outp,
    void* __restrict__ outp2, int nout, int ostride) {
  constexpr int KD = 2 * RAD + 1;
  constexpr int T = KD * KD;
  constexpr int KK = T * (CIN1 + CIN2);
  constexpr int WN = (BN >= 32) ? 2 : 1;
  constexpr int ROWS = (WN == 2) ? 1 : 2;
  constexpr int NFR = BN / (16 * WN);  // 128->4, 32->1, 16->1

  int tid = threadIdx.x, lane = tid & 63, wid = tid >> 6;
  int wm = wid / WN, wn = wid % WN;
  int l15 = lane & 15, lk = (lane >> 4) * 8;
  int r0 = blockIdx.x * ROWS;
  int ocb = blockIdx.y * BN + wn * (NFR * 16);

  f32x4 acc[4][NFR];
#pragma unroll
  for (int i = 0; i < 4; ++i)
#pragma unroll
    for (int j = 0; j < NFR; ++j) {
      acc[i][j][0] = 0.f; acc[i][j][1] = 0.f;
      acc[i][j][2] = 0.f; acc[i][j][3] = 0.f;
    }

  int py_r[4], px_m[4];
#pragma unroll
  for (int fm = 0; fm < 4; ++fm) {
    int m = wm * 64 + fm * 16 + l15;
    py_r[fm] = r0 + (m >> 7);
    px_m[fm] = m & 127;
  }

  const short* wrow = wb + (size_t)(ocb + l15) * KK + lk;

#pragma unroll 1
  for (int s = 0; s < T; ++s) {
    int dy = s / KD - RAD, dx = s % KD - RAD;
    mc_seg<CIN1, NFR, KK>(in1, wrow, s * CIN1, dy, dx, py_r, px_m, lk, acc);
  }
  if constexpr (CIN2 > 0) {
#pragma unroll 1
    for (int s = 0; s < T; ++s) {
      int dy = s / KD - RAD, dx = s % KD - RAD;
      mc_seg<CIN2, NFR, KK>(in2, wrow, T * CIN1 + s * CIN2, dy, dx, py_r, px_m,
                            lk, acc);
    }
  }

  // epilogue
#pragma unroll
  for (int fn = 0; fn < NFR; ++fn) {
    int ocx = ocb + fn * 16 + l15;
    float bv = 0.f;
    if (ocx < nout) {
      bv = bias1[ocx];
      if (bias2) bv += bias2[ocx];
    }
#pragma unroll
    for (int fm = 0; fm < 4; ++fm) {
#pragma unroll
      for (int j = 0; j < 4; ++j) {
        int m = wm * 64 + fm * 16 + (lane >> 4) * 4 + j;
        int row = r0 + (m >> 7);
        size_t pix = (size_t)row * 128 + (m & 127);
        float v = acc[fm][fn][j] + bv;
        if (LEAKY) v = leakyf(v);
        if (ocx < nout) {
          if constexpr (MODE == 1)
            ((__hip_bfloat16*)outp)[pix * ostride + ocx] = __float2bfloat16(v);
          else if constexpr (MODE == 0)
            ((float*)outp)[pix * ostride + ocx] = v;
          else {
            if (ocx < 256)
              ((float*)outp)[pix * 384 + ocx] += v;
            else
              ((float*)outp2)[pix * 128 + (ocx - 256)] = v;
          }
        }
      }
    }
  }
}

// ---------------------------------------------------------------------------
// Bilinear warp for all 5 flows. h_t: NHWC bf16 [npixc][128].
// flows: [pix][16] fp32 (cols 0..9 = (fx,fy) x 5). out: [pix][640] bf16.
__global__ __launch_bounds__(256) void k_warp5(
    const __hip_bfloat16* __restrict__ h_t, const float* __restrict__ flows,
    __hip_bfloat16* __restrict__ wout) {
  int t = threadIdx.x;
  int c = t & 127;
  size_t n = (size_t)blockIdx.x * 2 + (t >> 7);
  int b = (int)(n >> 14);
  int p = (int)(n & 16383);
  int y = p >> 7, x = p & 127;
  const __hip_bfloat16* base = h_t + (size_t)b * HW * 128;
#pragma unroll 1
  for (int l = 0; l < 5; ++l) {
    float fx = flows[n * 16 + 2 * l];
    float fy = flows[n * 16 + 2 * l + 1];
    float px = (float)x - fx;
    float py = (float)y - fy;
    float x0f = floorf(px), y0f = floorf(py);
    float wx = px - x0f, wy = py - y0f;
    int x0 = (int)x0f, y0i = (int)y0f;
    float v00 = 0.f, v10 = 0.f, v01 = 0.f, v11 = 0.f;
    if ((unsigned)x0 <= 127u && (unsigned)y0i <= 127u)
      v00 = __bfloat162float(base[((size_t)y0i * WW + x0) * 128 + c]);
    if ((unsigned)(x0 + 1) <= 127u && (unsigned)y0i <= 127u)
      v10 = __bfloat162float(base[((size_t)y0i * WW + (x0 + 1)) * 128 + c]);
    if ((unsigned)x0 <= 127u && (unsigned)(y0i + 1) <= 127u)
      v01 = __bfloat162float(base[((size_t)(y0i + 1) * WW + x0) * 128 + c]);
    if ((unsigned)(x0 + 1) <= 127u && (unsigned)(y0i + 1) <= 127u)
      v11 = __bfloat162float(base[((size_t)(y0i + 1) * WW + (x0 + 1)) * 128 + c]);
    float v = (1.f - wy) * ((1.f - wx) * v00 + wx * v10) +
              wy * ((1.f - wx) * v01 + wx * v11);
    wout[n * 640 + l * 128 + c] = __float2bfloat16(v);
  }
}

// ---------------------------------------------------------------------------
// Gates, coalesced. i2h: [pix][384] fp32 (r/u chunks already include h2h via
// ret-accum). h2h: [pix][128] fp32 (mem chunk). hpt: NHWC bf16 h_prev.
// FINAL=false: write NHWC bf16 (next step's input). FINAL=true: write NHWC f32.
template <bool FINAL>
__global__ __launch_bounds__(256) void k_gates2(
    const float* __restrict__ i2h, const float* __restrict__ h2h,
    const __hip_bfloat16* __restrict__ hpt, void* __restrict__ outp) {
  int tid = threadIdx.x;
  size_t n = (size_t)blockIdx.x * 8 + (tid >> 5);
  int c4 = (tid & 31) * 4;
  const float* irow = i2h + n * 384;
  f32x4 a0 = *(const f32x4*)(irow + c4);
  f32x4 a1 = *(const f32x4*)(irow + 128 + c4);
  f32x4 a2 = *(const f32x4*)(irow + 256 + c4);
  f32x4 b2 = *(const f32x4*)(h2h + n * 128 + c4);
  s16x4 hv = *(const s16x4*)((const short*)hpt + n * 128 + c4);
  if (FINAL) {
    f32x4 o;
#pragma unroll
    for (int j = 0; j < 4; ++j) {
      float r = sigmf_(a0[j]), u = sigmf_(a1[j]);
      float nm = leakyf(fmaf(r, b2[j], a2[j]));
      o[j] = u * bf2f(hv[j]) + (1.f - u) * nm;
    }
    *(f32x4*)((float*)outp + n * 128 + c4) = o;
  } else {
    s16x4 o;
#pragma unroll
    for (int j = 0; j < 4; ++j) {
      float r = sigmf_(a0[j]), u = sigmf_(a1[j]);
      float nm = leakyf(fmaf(r, b2[j], a2[j]));
      o[j] = f2bf(u * bf2f(hv[j]) + (1.f - u) * nm);
    }
    *(s16x4*)((short*)outp + n * 128 + c4) = o;
  }
}

// ---------------------------------------------------------------------------
extern "C" void kernel_launch(void* const* d_in, const int* in_sizes, int n_in,
                              void* d_out, int out_size, void* d_ws, size_t ws_size,
                              hipStream_t stream) {
  const float* x       = (const float*)d_in[0];
  const float* hp1     = (const float*)d_in[1];
  const float* hp2     = (const float*)d_in[2];
  const float* i2h_w1  = (const float*)d_in[3];
  const float* i2h_b1  = (const float*)d_in[4];
  const float* i2f_w1  = (const float*)d_in[5];
  const float* i2f_b1  = (const float*)d_in[6];
  const float* h2f_w1  = (const float*)d_in[7];
  const float* h2f_b1  = (const float*)d_in[8];
  const float* flow_w1 = (const float*)d_in[9];
  const float* flow_b1 = (const float*)d_in[10];
  const float* ret_w1  = (const float*)d_in[11];
  const float* ret_b1  = (const float*)d_in[12];
  const float* i2h_w2  = (const float*)d_in[13];
  const float* i2h_b2  = (const float*)d_in[14];
  const float* i2f_w2  = (const float*)d_in[15];
  const float* i2f_b2  = (const float*)d_in[16];
  const float* h2f_w2  = (const float*)d_in[17];
  const float* h2f_b2  = (const float*)d_in[18];
  const float* flow_w2 = (const float*)d_in[19];
  const float* flow_b2 = (const float*)d_in[20];
  const float* ret_w2  = (const float*)d_in[21];
  const float* ret_b2  = (const float*)d_in[22];
  float* out = (float*)d_out;

  // ---- workspace layout ----
  const size_t nWb3_1 = (size_t)384 * 576;
  const size_t nWb3_2 = (size_t)384 * 1152;
  const size_t nWbf1  = (size_t)32 * 4800;
  const size_t nWbf2  = (size_t)32 * 6400;
  const size_t nWfl   = (size_t)16 * 800;
  const size_t nWret  = (size_t)384 * 640;
  const size_t wtot = nWb3_1 + nWb3_2 + nWbf1 + nWbf2 + 2 * nWfl + 2 * nWret;

  // activation bytes/pixel: i2h 1536 + h2h 512 + warp5 1280 + h_t 256
  //                        + xb 256 + f1 64 + flows 64 = 3968
  int NBC = 8;
  while (NBC > 1 && wtot * 2 + (size_t)3968 * NBC * HW > ws_size)
    NBC >>= 1;
  const int npixc = NBC * HW;

  __hip_bfloat16* wbase = (__hip_bfloat16*)d_ws;
  __hip_bfloat16* Wb3_1 = wbase;
  __hip_bfloat16* Wb3_2 = Wb3_1 + nWb3_1;
  __hip_bfloat16* Wbf1  = Wb3_2 + nWb3_2;
  __hip_bfloat16* Wbf2  = Wbf1 + nWbf1;
  __hip_bfloat16* Wfl1  = Wbf2 + nWbf2;
  __hip_bfloat16* Wfl2  = Wfl1 + nWfl;
  __hip_bfloat16* Wret1 = Wfl2 + nWfl;
  __hip_bfloat16* Wret2 = Wret1 + nWret;

  char* abase = (char*)(Wret2 + nWret);
  float* i2hbuf = (float*)abase;                           // [npixc][384] f32
  float* h2hbuf = i2hbuf + (size_t)npixc * 384;            // [npixc][128] f32
  __hip_bfloat16* warpb5 = (__hip_bfloat16*)(h2hbuf + (size_t)npixc * 128); // [npixc][640]
  __hip_bfloat16* h_t = warpb5 + (size_t)npixc * 640;      // [npixc][128]
  __hip_bfloat16* xb  = h_t + (size_t)npixc * 128;         // [npixc][<=128]
  __hip_bfloat16* f1b = xb + (size_t)npixc * 128;          // [npixc][32]
  float* flowsb = (float*)(f1b + (size_t)npixc * 32);      // [npixc][16] f32
  float* go = (float*)warpb5;                              // [npixc][128] f32 (aliases warpb5)

  dim3 blk(256);
  auto packs = [&](const float* src, __hip_bfloat16* dst, int OC, int CINs,
                   int T, int kbase, int KK) {
    int n = OC * CINs * T;
    k_pack<<<dim3((n + 255) / 256), blk, 0, stream>>>(src, dst, OC, CINs, T,
                                                      kbase, KK);
  };
  packs(i2h_w1, Wb3_1, 384, 64, 9, 0, 576);
  packs(i2h_w2, Wb3_2, 384, 128, 9, 0, 1152);
  packs(i2f_w1, Wbf1, 32, 64, 25, 0, 4800);
  packs(h2f_w1, Wbf1, 32, 128, 25, 1600, 4800);
  packs(i2f_w2, Wbf2, 32, 128, 25, 0, 6400);
  packs(h2f_w2, Wbf2, 32, 128, 25, 3200, 6400);
  packs(flow_w1, Wfl1, 10, 32, 25, 0, 800);
  packs(flow_w2, Wfl2, 10, 32, 25, 0, 800);
  packs(ret_w1, Wret1, 384, 640, 1, 0, 640);
  packs(ret_w2, Wret2, 384, 640, 1, 0, 640);

  for (int b0 = 0; b0 < 8; b0 += NBC) {
    const float* xc   = x + (size_t)b0 * 64 * HW;
    const float* hp1c = hp1 + (size_t)b0 * 128 * HW;
    const float* hp2c = hp2 + (size_t)b0 * 128 * HW;

    // ================= step 1 =================
    k_cast_nhwc<128><<<dim3(4, 4, NBC * 128), blk, 0, stream>>>(hp1c, h_t);
    k_cast_nhwc<64><<<dim3(4, 2, NBC * 128), blk, 0, stream>>>(xc, xb);
    k_mconv<64, 128, 2, 32, true, 1><<<dim3(NBC * 128, 1), blk, 0, stream>>>(
        (const short*)xb, (const short*)h_t, (const short*)Wbf1, i2f_b1,
        h2f_b1, f1b, nullptr, 32, 32);
    k_mconv<32, 0, 2, 16, false, 0><<<dim3(NBC * 64, 1), blk, 0, stream>>>(
        (const short*)f1b, nullptr, (const short*)Wfl1, flow_b1, nullptr,
        flowsb, nullptr, 10, 16);
    k_mconv<64, 0, 1, 128, false, 0><<<dim3(NBC * 128, 3), blk, 0, stream>>>(
        (const short*)xb, nullptr, (const short*)Wb3_1, i2h_b1, nullptr,
        i2hbuf, nullptr, 384, 384);
    k_warp5<<<dim3(npixc / 2), blk, 0, stream>>>(h_t, flowsb, warpb5);
    k_mconv<640, 0, 0, 128, false, 2><<<dim3(NBC * 128, 3), blk, 0, stream>>>(
        (const short*)warpb5, nullptr, (const short*)Wret1, ret_b1, nullptr,
        i2hbuf, h2hbuf, 384, 384);
    // h1 written directly as NHWC bf16 into xb (step 2's input)
    k_gates2<false><<<dim3(npixc / 8), blk, 0, stream>>>(i2hbuf, h2hbuf, h_t, xb);

    // ================= step 2 =================
    k_cast_nhwc<128><<<dim3(4, 4, NBC * 128), blk, 0, stream>>>(hp2c, h_t);
    k_mconv<128, 128, 2, 32, true, 1><<<dim3(NBC * 128, 1), blk, 0, stream>>>(
        (const short*)xb, (const short*)h_t, (const short*)Wbf2, i2f_b2,
        h2f_b2, f1b, nullptr, 32, 32);
    k_mconv<32, 0, 2, 16, false, 0><<<dim3(NBC * 64, 1), blk, 0, stream>>>(
        (const short*)f1b, nullptr, (const short*)Wfl2, flow_b2, nullptr,
        flowsb, nullptr, 10, 16);
    k_mconv<128, 0, 1, 128, false, 0><<<dim3(NBC * 128, 3), blk, 0, stream>>>(
        (const short*)xb, nullptr, (const short*)Wb3_2, i2h_b2, nullptr,
        i2hbuf, nullptr, 384, 384);
    k_warp5<<<dim3(npixc / 2), blk, 0, stream>>>(h_t, flowsb, warpb5);
    k_mconv<640, 0, 0, 128, false, 2><<<dim3(NBC * 128, 3), blk, 0, stream>>>(
        (const short*)warpb5, nullptr, (const short*)Wret2, ret_b2, nullptr,
        i2hbuf, h2hbuf, 384, 384);
    k_gates2<true><<<dim3(npixc / 8), blk, 0, stream>>>(i2hbuf, h2hbuf, h_t, go);
    k_tonchw<<<dim3(4, 4, NBC * 128), blk, 0, stream>>>(go, out + (size_t)b0 * 128 * HW);
  }
}